// Round 1
// baseline (347.494 us; speedup 1.0000x reference)
//
#include <hip/hip_runtime.h>
#include <hip/hip_bf16.h>
#include <math.h>

#define H 128
#define EPS 1e-5f
#define INF_BIAS 0.1f
#define TM 64   // rows per projection block

// ---------------------------------------------------------------------------
// Kernel 1: fused projection GEMM + BN-affine fold.
//   user mode: U[r][j] = a_j * (z_user[r] . W1[j][0:128])   + (a_j*(b1_j-rm_j)+beta_j)
//   food mode: F[r][j] = a_j * (z_food[r] . W1[j][128:256])
// where a_j = gamma_j * rsqrt(rv_j + eps).
// Block: 512 threads, 64 rows x 128 cols tile, 4x4 microtile per thread.
// LDS: WsT[k][j] 64KB (transposed for conflict-free float4 reads) + Zs[k][r] 32KB.
// ---------------------------------------------------------------------------
__global__ __launch_bounds__(512) void proj_kernel(
    const float* __restrict__ z_user, const float* __restrict__ z_food,
    const float* __restrict__ W1,
    const float* __restrict__ b1, const float* __restrict__ gamma,
    const float* __restrict__ beta, const float* __restrict__ rm,
    const float* __restrict__ rv,
    float* __restrict__ U, float* __restrict__ F,
    int n_users, int n_foods, int UB)
{
    __shared__ float WsT[H][H];    // [k][j] : 64 KB
    __shared__ float Zs[H][TM];    // [k][r] : 32 KB

    const bool userMode = (blockIdx.x < (unsigned)UB);
    const float* Z;
    float* Out;
    int n, kOff, rBase;
    if (userMode) { Z = z_user; Out = U; n = n_users; kOff = 0; rBase = blockIdx.x * TM; }
    else          { Z = z_food; Out = F; n = n_foods; kOff = H; rBase = (blockIdx.x - UB) * TM; }

    const int t = threadIdx.x;

    // ---- stage W slice (128x128) transposed: thread -> row j = t/4, k0 = (t%4)*32
    {
        int j  = t >> 2;
        int k0 = (t & 3) << 5;
        const float4* src = (const float4*)(W1 + (size_t)j * (2 * H) + kOff + k0);
        #pragma unroll
        for (int i = 0; i < 8; ++i) {
            float4 v = src[i];
            int k = k0 + i * 4;
            WsT[k + 0][j] = v.x; WsT[k + 1][j] = v.y;
            WsT[k + 2][j] = v.z; WsT[k + 3][j] = v.w;
        }
    }
    // ---- stage Z tile (64 rows x 128) transposed: thread -> r = t/8, k0 = (t%8)*16
    {
        int r  = t >> 3;
        int k0 = (t & 7) << 4;
        int rL = min(rBase + r, n - 1);         // clamp for partial last block
        const float4* src = (const float4*)(Z + (size_t)rL * H + k0);
        #pragma unroll
        for (int i = 0; i < 4; ++i) {
            float4 v = src[i];
            int k = k0 + i * 4;
            Zs[k + 0][r] = v.x; Zs[k + 1][r] = v.y;
            Zs[k + 2][r] = v.z; Zs[k + 3][r] = v.w;
        }
    }
    __syncthreads();

    // ---- 4x4 microtile: 32 threads over cols, 16 over rows
    const int tc = t & 31, tr = t >> 5;
    const int j0 = tc << 2, r0 = tr << 2;

    float acc[4][4] = {};
    #pragma unroll 8
    for (int k = 0; k < H; ++k) {
        float4 wv = *(const float4*)&WsT[k][j0];   // lanes cover all banks / broadcast
        float4 zv = *(const float4*)&Zs[k][r0];    // wave-half broadcast
        acc[0][0] += zv.x * wv.x; acc[0][1] += zv.x * wv.y; acc[0][2] += zv.x * wv.z; acc[0][3] += zv.x * wv.w;
        acc[1][0] += zv.y * wv.x; acc[1][1] += zv.y * wv.y; acc[1][2] += zv.y * wv.z; acc[1][3] += zv.y * wv.w;
        acc[2][0] += zv.z * wv.x; acc[2][1] += zv.z * wv.y; acc[2][2] += zv.z * wv.z; acc[2][3] += zv.z * wv.w;
        acc[3][0] += zv.w * wv.x; acc[3][1] += zv.w * wv.y; acc[3][2] += zv.w * wv.z; acc[3][3] += zv.w * wv.w;
    }

    // ---- epilogue: fold BN affine (and b1 for user table)
    float a[4], d[4];
    #pragma unroll
    for (int i = 0; i < 4; ++i) {
        int j = j0 + i;
        float s  = rsqrtf(rv[j] + EPS);
        float aj = gamma[j] * s;
        a[i] = aj;
        d[i] = userMode ? (aj * (b1[j] - rm[j]) + beta[j]) : 0.0f;
    }
    #pragma unroll
    for (int m = 0; m < 4; ++m) {
        int r = rBase + r0 + m;
        if (r < n) {
            float4 o;
            o.x = a[0] * acc[m][0] + d[0];
            o.y = a[1] * acc[m][1] + d[1];
            o.z = a[2] * acc[m][2] + d[2];
            o.w = a[3] * acc[m][3] + d[3];
            *(float4*)&Out[(size_t)r * H + j0] = o;
        }
    }
}

// ---------------------------------------------------------------------------
// Kernel 2: per-edge gather + relu-dot + sigmoid.
// 16 lanes per edge; lane loads float4 pairs from U[row] and F[col] (512B
// coalesced row bursts), computes 8 relu-weighted terms, width-16 shuffle
// reduction, lane 0 writes sigmoid.
// ---------------------------------------------------------------------------
__global__ __launch_bounds__(256) void edge_kernel(
    const float* __restrict__ U, const float* __restrict__ F,
    const int* __restrict__ row, const int* __restrict__ col,
    const float* __restrict__ W2, const float* __restrict__ b2,
    float* __restrict__ out, int E)
{
    const int lane = threadIdx.x & 15;
    const int g       = (blockIdx.x * blockDim.x + threadIdx.x) >> 4;
    const int nGroups = (gridDim.x * blockDim.x) >> 4;

    // W2 fragment is a pure function of lane -> preload once
    const float4 w2a = ((const float4*)W2)[lane];
    const float4 w2b = ((const float4*)W2)[16 + lane];
    const float bias = b2[0] + INF_BIAS;

    for (int e = g; e < E; e += nGroups) {
        int u = row[e];
        int f = col[e];
        const float4* Ur = (const float4*)(U + (size_t)u * H);
        const float4* Fr = (const float4*)(F + (size_t)f * H);
        float4 ua = Ur[lane],      fa = Fr[lane];
        float4 ub = Ur[16 + lane], fb = Fr[16 + lane];

        float s =
            w2a.x * fmaxf(ua.x + fa.x, 0.0f) +
            w2a.y * fmaxf(ua.y + fa.y, 0.0f) +
            w2a.z * fmaxf(ua.z + fa.z, 0.0f) +
            w2a.w * fmaxf(ua.w + fa.w, 0.0f) +
            w2b.x * fmaxf(ub.x + fb.x, 0.0f) +
            w2b.y * fmaxf(ub.y + fb.y, 0.0f) +
            w2b.z * fmaxf(ub.z + fb.z, 0.0f) +
            w2b.w * fmaxf(ub.w + fb.w, 0.0f);

        s += __shfl_xor(s, 8, 16);
        s += __shfl_xor(s, 4, 16);
        s += __shfl_xor(s, 2, 16);
        s += __shfl_xor(s, 1, 16);

        if (lane == 0) {
            float x = s + bias;
            out[e] = 1.0f / (1.0f + __expf(-x));
        }
    }
}

extern "C" void kernel_launch(void* const* d_in, const int* in_sizes, int n_in,
                              void* d_out, int out_size, void* d_ws, size_t ws_size,
                              hipStream_t stream) {
    const float* z_user = (const float*)d_in[0];
    const float* z_food = (const float*)d_in[1];
    const int*   row    = (const int*)d_in[2];
    const int*   col    = (const int*)d_in[3];
    const float* W1     = (const float*)d_in[4];
    const float* b1     = (const float*)d_in[5];
    const float* gamma  = (const float*)d_in[6];
    const float* beta   = (const float*)d_in[7];
    const float* rm     = (const float*)d_in[8];
    const float* rv     = (const float*)d_in[9];
    const float* W2     = (const float*)d_in[10];
    const float* b2     = (const float*)d_in[11];
    float* out = (float*)d_out;

    const int n_users = in_sizes[0] / H;
    const int n_foods = in_sizes[1] / H;
    const int E       = in_sizes[2];

    // workspace: U (n_users x 128 f32) then F (n_foods x 128 f32) ~ 77 MB
    float* U = (float*)d_ws;
    float* F = U + (size_t)n_users * H;

    const int UB = (n_users + TM - 1) / TM;
    const int FB = (n_foods + TM - 1) / TM;

    proj_kernel<<<UB + FB, 512, 0, stream>>>(z_user, z_food, W1, b1, gamma, beta,
                                             rm, rv, U, F, n_users, n_foods, UB);

    edge_kernel<<<8192, 256, 0, stream>>>(U, F, row, col, W2, b2, out, E);
}

// Round 2
// 294.262 us; speedup vs baseline: 1.1809x; 1.1809x over previous
//
#include <hip/hip_runtime.h>
#include <hip/hip_bf16.h>
#include <math.h>

#define H 128
#define EPS 1e-5f
#define INF_BIAS 0.1f
#define TM 64   // rows per projection block

// ---- bf16 pack/unpack helpers (RNE, bit-exact with hardware bf16 rounding) ----
__device__ inline unsigned short f2bf_rne(float f) {
    unsigned u = __float_as_uint(f);
    u += 0x7fffu + ((u >> 16) & 1u);
    return (unsigned short)(u >> 16);
}
__device__ inline unsigned pack2(float a, float b) {
    return (unsigned)f2bf_rne(a) | ((unsigned)f2bf_rne(b) << 16);
}
__device__ inline float2 unpack2(unsigned v) {
    float2 r;
    r.x = __uint_as_float(v << 16);
    r.y = __uint_as_float(v & 0xffff0000u);
    return r;
}

// ---------------------------------------------------------------------------
// Kernel 1: fused projection GEMM + BN-affine fold, bf16 output tables.
//   user mode: U[r][j] = a_j * (z_user[r] . W1[j][0:128])   + (a_j*(b1_j-rm_j)+beta_j)
//   food mode: F[r][j] = a_j * (z_food[r] . W1[j][128:256])
// f32 compute, bf16 store. 512 threads, 64x128 tile, 4x4 microtile.
// ---------------------------------------------------------------------------
__global__ __launch_bounds__(512) void proj_kernel(
    const float* __restrict__ z_user, const float* __restrict__ z_food,
    const float* __restrict__ W1,
    const float* __restrict__ b1, const float* __restrict__ gamma,
    const float* __restrict__ beta, const float* __restrict__ rm,
    const float* __restrict__ rv,
    unsigned short* __restrict__ U, unsigned short* __restrict__ F,
    int n_users, int n_foods, int UB)
{
    __shared__ float WsT[H][H];    // [k][j] : 64 KB
    __shared__ float Zs[H][TM];    // [k][r] : 32 KB

    const bool userMode = (blockIdx.x < (unsigned)UB);
    const float* Z;
    unsigned short* Out;
    int n, kOff, rBase;
    if (userMode) { Z = z_user; Out = U; n = n_users; kOff = 0; rBase = blockIdx.x * TM; }
    else          { Z = z_food; Out = F; n = n_foods; kOff = H; rBase = (blockIdx.x - UB) * TM; }

    const int t = threadIdx.x;

    // ---- stage W slice (128x128) transposed
    {
        int j  = t >> 2;
        int k0 = (t & 3) << 5;
        const float4* src = (const float4*)(W1 + (size_t)j * (2 * H) + kOff + k0);
        #pragma unroll
        for (int i = 0; i < 8; ++i) {
            float4 v = src[i];
            int k = k0 + i * 4;
            WsT[k + 0][j] = v.x; WsT[k + 1][j] = v.y;
            WsT[k + 2][j] = v.z; WsT[k + 3][j] = v.w;
        }
    }
    // ---- stage Z tile (64 rows x 128) transposed
    {
        int r  = t >> 3;
        int k0 = (t & 7) << 4;
        int rL = min(rBase + r, n - 1);
        const float4* src = (const float4*)(Z + (size_t)rL * H + k0);
        #pragma unroll
        for (int i = 0; i < 4; ++i) {
            float4 v = src[i];
            int k = k0 + i * 4;
            Zs[k + 0][r] = v.x; Zs[k + 1][r] = v.y;
            Zs[k + 2][r] = v.z; Zs[k + 3][r] = v.w;
        }
    }
    __syncthreads();

    const int tc = t & 31, tr = t >> 5;
    const int j0 = tc << 2, r0 = tr << 2;

    float acc[4][4] = {};
    #pragma unroll 8
    for (int k = 0; k < H; ++k) {
        float4 wv = *(const float4*)&WsT[k][j0];
        float4 zv = *(const float4*)&Zs[k][r0];   // 2 distinct addrs/wave -> broadcast
        acc[0][0] += zv.x * wv.x; acc[0][1] += zv.x * wv.y; acc[0][2] += zv.x * wv.z; acc[0][3] += zv.x * wv.w;
        acc[1][0] += zv.y * wv.x; acc[1][1] += zv.y * wv.y; acc[1][2] += zv.y * wv.z; acc[1][3] += zv.y * wv.w;
        acc[2][0] += zv.z * wv.x; acc[2][1] += zv.z * wv.y; acc[2][2] += zv.z * wv.z; acc[2][3] += zv.z * wv.w;
        acc[3][0] += zv.w * wv.x; acc[3][1] += zv.w * wv.y; acc[3][2] += zv.w * wv.z; acc[3][3] += zv.w * wv.w;
    }

    // ---- epilogue: fold BN affine, round to bf16, 8B stores
    float a[4], d[4];
    #pragma unroll
    for (int i = 0; i < 4; ++i) {
        int j = j0 + i;
        float s  = rsqrtf(rv[j] + EPS);
        float aj = gamma[j] * s;
        a[i] = aj;
        d[i] = userMode ? (aj * (b1[j] - rm[j]) + beta[j]) : 0.0f;
    }
    #pragma unroll
    for (int m = 0; m < 4; ++m) {
        int r = rBase + r0 + m;
        if (r < n) {
            float ox = a[0] * acc[m][0] + d[0];
            float oy = a[1] * acc[m][1] + d[1];
            float oz = a[2] * acc[m][2] + d[2];
            float ow = a[3] * acc[m][3] + d[3];
            uint2 p;
            p.x = pack2(ox, oy);
            p.y = pack2(oz, ow);
            *(uint2*)&Out[(size_t)r * H + j0] = p;
        }
    }
}

// ---------------------------------------------------------------------------
// Kernel 2: per-edge gather + relu-dot + sigmoid, bf16 tables.
// 16 lanes/edge: lane loads one uint4 (8 bf16) from each table row (256B
// coalesced bursts), f32 accumulate, width-16 shuffle reduce.
// ---------------------------------------------------------------------------
__global__ __launch_bounds__(256) void edge_kernel(
    const unsigned short* __restrict__ U, const unsigned short* __restrict__ F,
    const int* __restrict__ row, const int* __restrict__ col,
    const float* __restrict__ W2, const float* __restrict__ b2,
    float* __restrict__ out, int E)
{
    const int lane = threadIdx.x & 15;
    const int g       = (blockIdx.x * blockDim.x + threadIdx.x) >> 4;
    const int nGroups = (gridDim.x * blockDim.x) >> 4;

    // lane covers elements [8*lane, 8*lane+8)
    const float4 w2a = ((const float4*)W2)[2 * lane];
    const float4 w2b = ((const float4*)W2)[2 * lane + 1];
    const float bias = b2[0] + INF_BIAS;

    for (int e = g; e < E; e += nGroups) {
        int u = row[e];
        int f = col[e];
        uint4 uv = ((const uint4*)(U + (size_t)u * H))[lane];
        uint4 fv = ((const uint4*)(F + (size_t)f * H))[lane];

        float2 u0 = unpack2(uv.x), f0 = unpack2(fv.x);
        float2 u1 = unpack2(uv.y), f1 = unpack2(fv.y);
        float2 u2 = unpack2(uv.z), f2 = unpack2(fv.z);
        float2 u3 = unpack2(uv.w), f3 = unpack2(fv.w);

        float s =
            w2a.x * fmaxf(u0.x + f0.x, 0.0f) +
            w2a.y * fmaxf(u0.y + f0.y, 0.0f) +
            w2a.z * fmaxf(u1.x + f1.x, 0.0f) +
            w2a.w * fmaxf(u1.y + f1.y, 0.0f) +
            w2b.x * fmaxf(u2.x + f2.x, 0.0f) +
            w2b.y * fmaxf(u2.y + f2.y, 0.0f) +
            w2b.z * fmaxf(u3.x + f3.x, 0.0f) +
            w2b.w * fmaxf(u3.y + f3.y, 0.0f);

        s += __shfl_xor(s, 8, 16);
        s += __shfl_xor(s, 4, 16);
        s += __shfl_xor(s, 2, 16);
        s += __shfl_xor(s, 1, 16);

        if (lane == 0) {
            float x = s + bias;
            out[e] = 1.0f / (1.0f + __expf(-x));
        }
    }
}

extern "C" void kernel_launch(void* const* d_in, const int* in_sizes, int n_in,
                              void* d_out, int out_size, void* d_ws, size_t ws_size,
                              hipStream_t stream) {
    const float* z_user = (const float*)d_in[0];
    const float* z_food = (const float*)d_in[1];
    const int*   row    = (const int*)d_in[2];
    const int*   col    = (const int*)d_in[3];
    const float* W1     = (const float*)d_in[4];
    const float* b1     = (const float*)d_in[5];
    const float* gamma  = (const float*)d_in[6];
    const float* beta   = (const float*)d_in[7];
    const float* rm     = (const float*)d_in[8];
    const float* rv     = (const float*)d_in[9];
    const float* W2     = (const float*)d_in[10];
    const float* b2     = (const float*)d_in[11];
    float* out = (float*)d_out;

    const int n_users = in_sizes[0] / H;
    const int n_foods = in_sizes[1] / H;
    const int E       = in_sizes[2];

    // workspace: U (n_users x 128 bf16) then F (n_foods x 128 bf16) ~ 38.5 MB
    unsigned short* U = (unsigned short*)d_ws;
    unsigned short* F = U + (size_t)n_users * H;   // byte offset multiple of 16

    const int UB = (n_users + TM - 1) / TM;
    const int FB = (n_foods + TM - 1) / TM;

    proj_kernel<<<UB + FB, 512, 0, stream>>>(z_user, z_food, W1, b1, gamma, beta,
                                             rm, rv, U, F, n_users, n_foods, UB);

    edge_kernel<<<8192, 256, 0, stream>>>(U, F, row, col, W2, b2, out, E);
}

// Round 3
// 281.211 us; speedup vs baseline: 1.2357x; 1.0464x over previous
//
#include <hip/hip_runtime.h>
#include <hip/hip_bf16.h>
#include <math.h>

#define H 128
#define EPS 1e-5f
#define INF_BIAS 0.1f

typedef __attribute__((ext_vector_type(8))) short bf16x8;
typedef __attribute__((ext_vector_type(4))) float f32x4;

// ---- bf16 helpers (RNE) ----
__device__ inline unsigned short f2bf_rne(float f) {
    unsigned u = __float_as_uint(f);
    u += 0x7fffu + ((u >> 16) & 1u);
    return (unsigned short)(u >> 16);
}
__device__ inline float bf2f(unsigned short h) {
    return __uint_as_float(((unsigned)h) << 16);
}
__device__ inline unsigned pack2(float a, float b) {
    return (unsigned)f2bf_rne(a) | ((unsigned)f2bf_rne(b) << 16);
}
__device__ inline float2 unpack2(unsigned v) {
    float2 r;
    r.x = __uint_as_float(v << 16);
    r.y = __uint_as_float(v & 0xffff0000u);
    return r;
}
// split f32 -> (hi, lo) bf16 pair: x ~= hi + lo with ~2^-16 relative error
__device__ inline void split_bf16(float x, unsigned short& hi, unsigned short& lo) {
    hi = f2bf_rne(x);
    lo = f2bf_rne(x - bf2f(hi));
}

// ---------------------------------------------------------------------------
// prep kernel: build BN-prescaled, hi/lo-split bf16 W tables + offset vector.
//   Ws_user[j][k] = a_j * W1[j][k],  Ws_food[j][k] = a_j * W1[j][128+k]
//   a_j = gamma_j * rsqrt(rv_j+eps);  d_user[j] = a_j*(b1_j-rm_j)+beta_j
// grid: 128 blocks (j) x 128 threads (k)
// ---------------------------------------------------------------------------
__global__ void prep_kernel(
    const float* __restrict__ W1, const float* __restrict__ b1,
    const float* __restrict__ gamma, const float* __restrict__ beta,
    const float* __restrict__ rm, const float* __restrict__ rv,
    unsigned short* __restrict__ Whi_u, unsigned short* __restrict__ Wlo_u,
    unsigned short* __restrict__ Whi_f, unsigned short* __restrict__ Wlo_f,
    float* __restrict__ d_user)
{
    int j = blockIdx.x;
    int k = threadIdx.x;
    float a = gamma[j] * rsqrtf(rv[j] + EPS);
    float wu = a * W1[(size_t)j * (2 * H) + k];
    float wf = a * W1[(size_t)j * (2 * H) + H + k];
    unsigned short hi, lo;
    split_bf16(wu, hi, lo);
    Whi_u[j * H + k] = hi; Wlo_u[j * H + k] = lo;
    split_bf16(wf, hi, lo);
    Whi_f[j * H + k] = hi; Wlo_f[j * H + k] = lo;
    if (k == 0) d_user[j] = a * (b1[j] - rm[j]) + beta[j];
}

// ---------------------------------------------------------------------------
// proj_mfma: table build via MFMA, split-bf16 (~f32 precision), bf16 output.
// 256 threads = 4 waves; each wave computes a 16-row x 128-col strip.
// No LDS: A-frags load straight from Z (f32, 32B/lane contiguous), B-frags
// from the L2-resident prep tables (16B/lane).
// ---------------------------------------------------------------------------
__global__ __launch_bounds__(256) void proj_mfma(
    const float* __restrict__ z_user, const float* __restrict__ z_food,
    const unsigned short* __restrict__ Whi_u, const unsigned short* __restrict__ Wlo_u,
    const unsigned short* __restrict__ Whi_f, const unsigned short* __restrict__ Wlo_f,
    const float* __restrict__ d_user,
    unsigned short* __restrict__ U, unsigned short* __restrict__ F,
    int n_users, int n_foods, int UB)
{
    const bool userMode = (blockIdx.x < (unsigned)UB);
    const float* Z;
    const unsigned short *Whi, *Wlo;
    unsigned short* Out;
    int n, tile;
    if (userMode) { Z = z_user; Whi = Whi_u; Wlo = Wlo_u; Out = U; n = n_users; tile = blockIdx.x; }
    else          { Z = z_food; Whi = Whi_f; Wlo = Wlo_f; Out = F; n = n_foods; tile = blockIdx.x - UB; }

    const int wave = threadIdx.x >> 6;
    const int lane = threadIdx.x & 63;
    const int m = lane & 15;        // row within strip (A) / col within tile (D)
    const int g = lane >> 4;        // quad: k-group for A/B, row-group for D

    const int rStrip = tile * 64 + wave * 16;
    const int rowIdx = min(rStrip + m, n - 1);
    const float* zrow = Z + (size_t)rowIdx * H;

    f32x4 acc[8];
    #pragma unroll
    for (int nt = 0; nt < 8; ++nt) acc[nt] = (f32x4){0.f, 0.f, 0.f, 0.f};

    #pragma unroll
    for (int kt = 0; kt < 4; ++kt) {
        const int k0 = kt * 32 + g * 8;
        // A fragment: 8 consecutive f32 from this lane's Z row
        float4 za = ((const float4*)(zrow + k0))[0];
        float4 zb = ((const float4*)(zrow + k0))[1];
        bf16x8 ahi, alo;
        {
            float v[8] = {za.x, za.y, za.z, za.w, zb.x, zb.y, zb.z, zb.w};
            #pragma unroll
            for (int i = 0; i < 8; ++i) {
                unsigned short hi, lo;
                split_bf16(v[i], hi, lo);
                ahi[i] = (short)hi; alo[i] = (short)lo;
            }
        }
        #pragma unroll
        for (int nt = 0; nt < 8; ++nt) {
            const size_t woff = (size_t)(nt * 16 + m) * H + k0;
            bf16x8 bhi = *(const bf16x8*)(Whi + woff);
            bf16x8 blo = *(const bf16x8*)(Wlo + woff);
            acc[nt] = __builtin_amdgcn_mfma_f32_16x16x32_bf16(ahi, bhi, acc[nt], 0, 0, 0);
            acc[nt] = __builtin_amdgcn_mfma_f32_16x16x32_bf16(ahi, blo, acc[nt], 0, 0, 0);
            acc[nt] = __builtin_amdgcn_mfma_f32_16x16x32_bf16(alo, bhi, acc[nt], 0, 0, 0);
        }
    }

    // epilogue: + d_j (user mode), round to bf16, store.
    // D layout: col = m (-> global col nt*16+m), row = g*4 + i (-> strip row)
    #pragma unroll
    for (int nt = 0; nt < 8; ++nt) {
        const int j = nt * 16 + m;
        const float d = userMode ? d_user[j] : 0.0f;
        #pragma unroll
        for (int i = 0; i < 4; ++i) {
            const int r = rStrip + g * 4 + i;
            if (r < n) Out[(size_t)r * H + j] = f2bf_rne(acc[nt][i] + d);
        }
    }
}

// ---------------------------------------------------------------------------
// edge kernel: per-edge gather + relu-dot + sigmoid, bf16 tables (unchanged).
// ---------------------------------------------------------------------------
__global__ __launch_bounds__(256) void edge_kernel(
    const unsigned short* __restrict__ U, const unsigned short* __restrict__ F,
    const int* __restrict__ row, const int* __restrict__ col,
    const float* __restrict__ W2, const float* __restrict__ b2,
    float* __restrict__ out, int E)
{
    const int lane = threadIdx.x & 15;
    const int g       = (blockIdx.x * blockDim.x + threadIdx.x) >> 4;
    const int nGroups = (gridDim.x * blockDim.x) >> 4;

    const float4 w2a = ((const float4*)W2)[2 * lane];
    const float4 w2b = ((const float4*)W2)[2 * lane + 1];
    const float bias = b2[0] + INF_BIAS;

    for (int e = g; e < E; e += nGroups) {
        int u = row[e];
        int f = col[e];
        uint4 uv = ((const uint4*)(U + (size_t)u * H))[lane];
        uint4 fv = ((const uint4*)(F + (size_t)f * H))[lane];

        float2 u0 = unpack2(uv.x), f0 = unpack2(fv.x);
        float2 u1 = unpack2(uv.y), f1 = unpack2(fv.y);
        float2 u2 = unpack2(uv.z), f2 = unpack2(fv.z);
        float2 u3 = unpack2(uv.w), f3 = unpack2(fv.w);

        float s =
            w2a.x * fmaxf(u0.x + f0.x, 0.0f) +
            w2a.y * fmaxf(u0.y + f0.y, 0.0f) +
            w2a.z * fmaxf(u1.x + f1.x, 0.0f) +
            w2a.w * fmaxf(u1.y + f1.y, 0.0f) +
            w2b.x * fmaxf(u2.x + f2.x, 0.0f) +
            w2b.y * fmaxf(u2.y + f2.y, 0.0f) +
            w2b.z * fmaxf(u3.x + f3.x, 0.0f) +
            w2b.w * fmaxf(u3.y + f3.y, 0.0f);

        s += __shfl_xor(s, 8, 16);
        s += __shfl_xor(s, 4, 16);
        s += __shfl_xor(s, 2, 16);
        s += __shfl_xor(s, 1, 16);

        if (lane == 0) {
            float x = s + bias;
            out[e] = 1.0f / (1.0f + __expf(-x));
        }
    }
}

extern "C" void kernel_launch(void* const* d_in, const int* in_sizes, int n_in,
                              void* d_out, int out_size, void* d_ws, size_t ws_size,
                              hipStream_t stream) {
    const float* z_user = (const float*)d_in[0];
    const float* z_food = (const float*)d_in[1];
    const int*   row    = (const int*)d_in[2];
    const int*   col    = (const int*)d_in[3];
    const float* W1     = (const float*)d_in[4];
    const float* b1     = (const float*)d_in[5];
    const float* gamma  = (const float*)d_in[6];
    const float* beta   = (const float*)d_in[7];
    const float* rm     = (const float*)d_in[8];
    const float* rv     = (const float*)d_in[9];
    const float* W2     = (const float*)d_in[10];
    const float* b2     = (const float*)d_in[11];
    float* out = (float*)d_out;

    const int n_users = in_sizes[0] / H;
    const int n_foods = in_sizes[1] / H;
    const int E       = in_sizes[2];

    // workspace layout (bf16 tables + split W + offsets)
    unsigned short* U     = (unsigned short*)d_ws;                 // n_users*128 bf16
    unsigned short* F     = U + (size_t)n_users * H;               // n_foods*128 bf16
    unsigned short* Whi_u = F + (size_t)n_foods * H;               // 128*128 each
    unsigned short* Wlo_u = Whi_u + H * H;
    unsigned short* Whi_f = Wlo_u + H * H;
    unsigned short* Wlo_f = Whi_f + H * H;
    float*          d_usr = (float*)(Wlo_f + H * H);               // 128 f32

    prep_kernel<<<H, H, 0, stream>>>(W1, b1, gamma, beta, rm, rv,
                                     Whi_u, Wlo_u, Whi_f, Wlo_f, d_usr);

    const int UB = (n_users + 63) / 64;
    const int FB = (n_foods + 63) / 64;
    proj_mfma<<<UB + FB, 256, 0, stream>>>(z_user, z_food,
                                           Whi_u, Wlo_u, Whi_f, Wlo_f, d_usr,
                                           U, F, n_users, n_foods, UB);

    edge_kernel<<<8192, 256, 0, stream>>>(U, F, row, col, W2, b2, out, E);
}

// Round 4
// 223.797 us; speedup vs baseline: 1.5527x; 1.2565x over previous
//
#include <hip/hip_runtime.h>
#include <hip/hip_bf16.h>
#include <math.h>

#define H 128
#define EPS 1e-5f
#define INF_BIAS 0.1f

typedef __attribute__((ext_vector_type(8))) short bf16x8;
typedef __attribute__((ext_vector_type(4))) float f32x4;

// ---- bf16 helpers (RNE) ----
__device__ inline unsigned short f2bf_rne(float f) {
    unsigned u = __float_as_uint(f);
    u += 0x7fffu + ((u >> 16) & 1u);
    return (unsigned short)(u >> 16);
}
__device__ inline float bf2f(unsigned short h) {
    return __uint_as_float(((unsigned)h) << 16);
}
__device__ inline unsigned pack2(float a, float b) {
    return (unsigned)f2bf_rne(a) | ((unsigned)f2bf_rne(b) << 16);
}
__device__ inline float2 unpack2(unsigned v) {
    float2 r;
    r.x = __uint_as_float(v << 16);
    r.y = __uint_as_float(v & 0xffff0000u);
    return r;
}

// ---------------------------------------------------------------------------
// prep: BN-prescaled bf16(hi) W tables + user offset vector.
//   Whi_u[j][k] = bf16(a_j * W1[j][k]);  Whi_f[j][k] = bf16(a_j * W1[j][128+k])
//   d_user[j]   = a_j*(b1_j - rm_j) + beta_j,  a_j = gamma_j*rsqrt(rv_j+eps)
// ---------------------------------------------------------------------------
__global__ void prep_kernel(
    const float* __restrict__ W1, const float* __restrict__ b1,
    const float* __restrict__ gamma, const float* __restrict__ beta,
    const float* __restrict__ rm, const float* __restrict__ rv,
    unsigned short* __restrict__ Whi_u, unsigned short* __restrict__ Whi_f,
    float* __restrict__ d_user)
{
    int j = blockIdx.x;
    int k = threadIdx.x;
    float a = gamma[j] * rsqrtf(rv[j] + EPS);
    Whi_u[j * H + k] = f2bf_rne(a * W1[(size_t)j * (2 * H) + k]);
    Whi_f[j * H + k] = f2bf_rne(a * W1[(size_t)j * (2 * H) + H + k]);
    if (k == 0) d_user[j] = a * (b1[j] - rm[j]) + beta[j];
}

// ---------------------------------------------------------------------------
// proj_mfma: W register-stationary MFMA table build.
// A = W (m=output col j), B = Z (n=row r), so each lane's 4 acc regs are 4
// consecutive cols of one row -> one 8B packed store per fragment.
// Each wave preloads 32 W-frags (128 VGPR) once, then grid-strides row-tiles.
// Z is split hi+lo bf16 (2 MFMAs) for ~f32 Z precision; W is bf16-hi.
// ---------------------------------------------------------------------------
__global__ __launch_bounds__(256, 2) void proj_mfma(
    const float* __restrict__ z_user, const float* __restrict__ z_food,
    const unsigned short* __restrict__ Whi_u, const unsigned short* __restrict__ Whi_f,
    const float* __restrict__ d_user,
    unsigned short* __restrict__ U, unsigned short* __restrict__ F,
    int n_users, int n_foods, int GU, int GB)
{
    const bool userMode = (blockIdx.x < (unsigned)GU);
    const float* Z;
    const unsigned short* Wt;
    unsigned short* Out;
    int n, blk0, nblk;
    if (userMode) { Z = z_user; Wt = Whi_u; Out = U; n = n_users; blk0 = blockIdx.x;      nblk = GU; }
    else          { Z = z_food; Wt = Whi_f; Out = F; n = n_foods; blk0 = blockIdx.x - GU; nblk = GB - GU; }
    const int tiles = (n + 15) >> 4;

    const int wave = threadIdx.x >> 6;
    const int lane = threadIdx.x & 63;
    const int c = lane & 15;   // D col  -> row r within tile; W row j0+c for A; Z row for B
    const int q = lane >> 4;   // quad   -> k-group for A/B; j-subgroup for D

    // ---- preload W fragments (register-stationary): wf[nt][kt]
    bf16x8 wf[8][4];
    #pragma unroll
    for (int nt = 0; nt < 8; ++nt)
        #pragma unroll
        for (int kt = 0; kt < 4; ++kt)
            wf[nt][kt] = *(const bf16x8*)(Wt + (size_t)(nt * 16 + c) * H + kt * 32 + q * 8);

    // ---- BN offset folded into accumulator init
    f32x4 dvec[8];
    #pragma unroll
    for (int nt = 0; nt < 8; ++nt) {
        if (userMode) {
            float4 d = *(const float4*)(d_user + nt * 16 + q * 4);
            dvec[nt] = (f32x4){d.x, d.y, d.z, d.w};
        } else {
            dvec[nt] = (f32x4){0.f, 0.f, 0.f, 0.f};
        }
    }

    const int wid = blk0 * 4 + wave;
    const int nw  = nblk * 4;

    for (int t = wid; t < tiles; t += nw) {
        const int r = t * 16 + c;
        const float* zrow = Z + (size_t)min(r, n - 1) * H;

        f32x4 acc[8];
        #pragma unroll
        for (int nt = 0; nt < 8; ++nt) acc[nt] = dvec[nt];

        #pragma unroll
        for (int kt = 0; kt < 4; ++kt) {
            const int k0 = kt * 32 + q * 8;
            float4 za = ((const float4*)(zrow + k0))[0];
            float4 zb = ((const float4*)(zrow + k0))[1];
            bf16x8 zhi, zlo;
            {
                float v[8] = {za.x, za.y, za.z, za.w, zb.x, zb.y, zb.z, zb.w};
                #pragma unroll
                for (int i = 0; i < 8; ++i) {
                    unsigned short hi = f2bf_rne(v[i]);
                    unsigned short lo = f2bf_rne(v[i] - bf2f(hi));
                    zhi[i] = (short)hi; zlo[i] = (short)lo;
                }
            }
            #pragma unroll
            for (int nt = 0; nt < 8; ++nt) {
                acc[nt] = __builtin_amdgcn_mfma_f32_16x16x32_bf16(wf[nt][kt], zhi, acc[nt], 0, 0, 0);
                acc[nt] = __builtin_amdgcn_mfma_f32_16x16x32_bf16(wf[nt][kt], zlo, acc[nt], 0, 0, 0);
            }
        }

        // ---- packed epilogue: lane (c,q) holds row r, cols nt*16+q*4+{0..3}
        if (r < n) {
            unsigned short* orow = Out + (size_t)r * H + q * 4;
            #pragma unroll
            for (int nt = 0; nt < 8; ++nt) {
                uint2 p;
                p.x = pack2(acc[nt][0], acc[nt][1]);
                p.y = pack2(acc[nt][2], acc[nt][3]);
                *(uint2*)(orow + nt * 16) = p;
            }
        }
    }
}

// ---------------------------------------------------------------------------
// edge kernel: per-edge gather + relu-dot + sigmoid, bf16 tables (unchanged).
// ---------------------------------------------------------------------------
__global__ __launch_bounds__(256) void edge_kernel(
    const unsigned short* __restrict__ U, const unsigned short* __restrict__ F,
    const int* __restrict__ row, const int* __restrict__ col,
    const float* __restrict__ W2, const float* __restrict__ b2,
    float* __restrict__ out, int E)
{
    const int lane = threadIdx.x & 15;
    const int g       = (blockIdx.x * blockDim.x + threadIdx.x) >> 4;
    const int nGroups = (gridDim.x * blockDim.x) >> 4;

    const float4 w2a = ((const float4*)W2)[2 * lane];
    const float4 w2b = ((const float4*)W2)[2 * lane + 1];
    const float bias = b2[0] + INF_BIAS;

    for (int e = g; e < E; e += nGroups) {
        int u = row[e];
        int f = col[e];
        uint4 uv = ((const uint4*)(U + (size_t)u * H))[lane];
        uint4 fv = ((const uint4*)(F + (size_t)f * H))[lane];

        float2 u0 = unpack2(uv.x), f0 = unpack2(fv.x);
        float2 u1 = unpack2(uv.y), f1 = unpack2(fv.y);
        float2 u2 = unpack2(uv.z), f2 = unpack2(fv.z);
        float2 u3 = unpack2(uv.w), f3 = unpack2(fv.w);

        float s =
            w2a.x * fmaxf(u0.x + f0.x, 0.0f) +
            w2a.y * fmaxf(u0.y + f0.y, 0.0f) +
            w2a.z * fmaxf(u1.x + f1.x, 0.0f) +
            w2a.w * fmaxf(u1.y + f1.y, 0.0f) +
            w2b.x * fmaxf(u2.x + f2.x, 0.0f) +
            w2b.y * fmaxf(u2.y + f2.y, 0.0f) +
            w2b.z * fmaxf(u3.x + f3.x, 0.0f) +
            w2b.w * fmaxf(u3.y + f3.y, 0.0f);

        s += __shfl_xor(s, 8, 16);
        s += __shfl_xor(s, 4, 16);
        s += __shfl_xor(s, 2, 16);
        s += __shfl_xor(s, 1, 16);

        if (lane == 0) {
            float x = s + bias;
            out[e] = 1.0f / (1.0f + __expf(-x));
        }
    }
}

extern "C" void kernel_launch(void* const* d_in, const int* in_sizes, int n_in,
                              void* d_out, int out_size, void* d_ws, size_t ws_size,
                              hipStream_t stream) {
    const float* z_user = (const float*)d_in[0];
    const float* z_food = (const float*)d_in[1];
    const int*   row    = (const int*)d_in[2];
    const int*   col    = (const int*)d_in[3];
    const float* W1     = (const float*)d_in[4];
    const float* b1     = (const float*)d_in[5];
    const float* gamma  = (const float*)d_in[6];
    const float* beta   = (const float*)d_in[7];
    const float* rm     = (const float*)d_in[8];
    const float* rv     = (const float*)d_in[9];
    const float* W2     = (const float*)d_in[10];
    const float* b2     = (const float*)d_in[11];
    float* out = (float*)d_out;

    const int n_users = in_sizes[0] / H;
    const int n_foods = in_sizes[1] / H;
    const int E       = in_sizes[2];

    // workspace layout
    unsigned short* U     = (unsigned short*)d_ws;        // n_users*128 bf16
    unsigned short* F     = U + (size_t)n_users * H;      // n_foods*128 bf16
    unsigned short* Whi_u = F + (size_t)n_foods * H;      // 128*128 bf16
    unsigned short* Whi_f = Whi_u + H * H;                // 128*128 bf16
    float*          d_usr = (float*)(Whi_f + H * H);      // 128 f32

    prep_kernel<<<H, H, 0, stream>>>(W1, b1, gamma, beta, rm, rv,
                                     Whi_u, Whi_f, d_usr);

    // 2:1 block split matches the 2:1 user:food row ratio; ~2 blocks/CU
    const int GU = 344, GB = 516;
    proj_mfma<<<GB, 256, 0, stream>>>(z_user, z_food, Whi_u, Whi_f, d_usr,
                                      U, F, n_users, n_foods, GU, GB);

    edge_kernel<<<8192, 256, 0, stream>>>(U, F, row, col, W2, b2, out, E);
}